// Round 3
// baseline (1280.844 us; speedup 1.0000x reference)
//
#include <hip/hip_runtime.h>
#include <math.h>

typedef __bf16 bf16;
typedef __attribute__((ext_vector_type(8))) __bf16 bf16x8;
typedef __attribute__((ext_vector_type(4))) __bf16 bf16x4;
typedef __attribute__((ext_vector_type(2))) __bf16 bf16x2;
typedef __attribute__((ext_vector_type(4))) float f32x4;

#define DIM 2048
#define NH 16
#define DKK 128
#define BATCH 4
#define SEQ 4096
#define BN (BATCH*SEQ)
#define INV_SQRT_DK 0.08838834764831845f

#define MFMA16(a,b,c) __builtin_amdgcn_mfma_f32_16x16x32_bf16((a),(b),(c),0,0,0)

#define GLDS(gp, lp) __builtin_amdgcn_global_load_lds( \
    (const __attribute__((address_space(1))) void*)(gp), \
    (__attribute__((address_space(3))) void*)(lp), 16, 0, 0)

// stage a 128x64 bf16 tile (row stride ld in global) into LDS (stride 64, chunk-XOR swizzle)
__device__ inline void stage_tile(const bf16* __restrict__ g, int ld,
                                  bf16* lds, int lane, int wave) {
  const int rl = lane >> 3;                      // 0..7 row within 8-row group
  const int gc = ((lane & 7) ^ (rl & 7)) << 3;   // swizzled source chunk (elements)
  const bf16* gp = g + (size_t)(wave * 32 + rl) * ld + gc;
#pragma unroll
  for (int t = 0; t < 4; ++t)
    GLDS(gp + (size_t)(t * 8) * ld, lds + (wave * 32 + t * 8) * 64);
}

// read 8 consecutive (global-k) elements for row r at global chunk kc from a swizzled 64-stride tile
__device__ inline bf16x8 frag8(const bf16* lds, int r, int kc) {
  return *(const bf16x8*)(lds + r * 64 + (((kc ^ (r & 7)) << 3)));
}

// swizzled 128-stride tile helpers
__device__ inline bf16x8 frag8w(const bf16* lds, int r, int kc) {
  return *(const bf16x8*)(lds + r * 128 + (((kc ^ (r & 7)) << 3)));
}
__device__ inline int sqaddr(int r, int c) {  // scalar element address in swizzled 128-stride tile
  return r * 128 + ((((c >> 3) ^ (r & 7)) << 3) | (c & 7));
}

__device__ inline float fast_exp(float x) { return __expf(x); }
__device__ inline float fast_tanh(float x) {
  float e2 = __expf(2.f * x);
  return 1.f - 2.f / (e2 + 1.f);
}

// ---------------- conversion kernels ----------------
__global__ __launch_bounds__(256) void conv_bf16(const float* __restrict__ x,
                                                 bf16* __restrict__ y) {
  int i = (blockIdx.x * 256 + threadIdx.x) * 4;
  float4 v = *(const float4*)(x + i);
  bf16x4 o = { (bf16)v.x, (bf16)v.y, (bf16)v.z, (bf16)v.w };
  *(bf16x4*)(y + i) = o;
}

// 4 fused 2048x2048 transposes selected by blockIdx.z
__global__ __launch_bounds__(256) void tconv4(const float* W0, const float* W1,
                                              const float* W2, const float* W3,
                                              bf16* O0, bf16* O1, bf16* O2, bf16* O3) {
  __shared__ float tile[32][33];
  const float* Wp; bf16* Op;
  switch (blockIdx.z) {
    case 0: Wp = W0; Op = O0; break;
    case 1: Wp = W1; Op = O1; break;
    case 2: Wp = W2; Op = O2; break;
    default: Wp = W3; Op = O3; break;
  }
  int c0 = blockIdx.x * 32, r0 = blockIdx.y * 32;
  int tx = threadIdx.x, ty = threadIdx.y;  // (32,8)
#pragma unroll
  for (int i = 0; i < 4; ++i)
    tile[ty + i*8][tx] = Wp[(size_t)(r0 + ty + i*8) * DIM + c0 + tx];
  __syncthreads();
#pragma unroll
  for (int i = 0; i < 4; ++i)
    Op[(size_t)(c0 + ty + i*8) * DIM + r0 + tx] = (bf16)tile[tx][ty + i*8];
}

// per-head 128x128 transpose for W_bilinear
__global__ __launch_bounds__(256) void tconvWb(const float* __restrict__ W,
                                               bf16* __restrict__ Wt) {
  __shared__ float tile[32][33];
  const float* Wp = W + (size_t)blockIdx.z * DKK * DKK;
  bf16* Wtp = Wt + (size_t)blockIdx.z * DKK * DKK;
  int c0 = blockIdx.x * 32, r0 = blockIdx.y * 32;
  int tx = threadIdx.x, ty = threadIdx.y;
#pragma unroll
  for (int i = 0; i < 4; ++i)
    tile[ty + i*8][tx] = Wp[(size_t)(r0 + ty + i*8) * DKK + c0 + tx];
  __syncthreads();
#pragma unroll
  for (int i = 0; i < 4; ++i)
    Wtp[(size_t)(c0 + ty + i*8) * DKK + r0 + tx] = (bf16)tile[tx][ty + i*8];
}

// rbuf[h][n] = exp((fs[h]-ss[h])*(n-(SEQ-1)))
__global__ __launch_bounds__(256) void rweights(const float* __restrict__ fs,
                                                const float* __restrict__ ss,
                                                float* __restrict__ rbuf) {
  int n = blockIdx.x * 256 + threadIdx.x;
  int h = blockIdx.y;
  rbuf[h * SEQ + n] = fast_exp((fs[h] - ss[h]) * (float)(n - (SEQ - 1)));
}

// ---------------- mean + MLP (psi) ----------------
__global__ void zero_f32(float* p, int n) {
  int i = blockIdx.x * 256 + threadIdx.x;
  if (i < n) p[i] = 0.f;
}

__global__ __launch_bounds__(256) void mean_part(const bf16* __restrict__ xb,
                                                 float* __restrict__ xm) {
  int d0 = (blockIdx.x * 256 + threadIdx.x) * 2;
  int b = blockIdx.z;
  const bf16* xp = xb + ((size_t)b * SEQ + (size_t)blockIdx.y * 256) * DIM + d0;
  float s0 = 0.f, s1 = 0.f;
#pragma unroll 8
  for (int n = 0; n < 256; ++n) {
    bf16x2 v = *(const bf16x2*)(xp + (size_t)n * DIM);
    s0 += (float)v[0]; s1 += (float)v[1];
  }
  atomicAdd(&xm[b * DIM + d0], s0);
  atomicAdd(&xm[b * DIM + d0 + 1], s1);
}

// partial dot over k-split; h1raw accumulates raw (unscaled) sums
__global__ __launch_bounds__(256) void mlp1(const float* __restrict__ xm,
                                            const float* __restrict__ f1w,
                                            float* __restrict__ h1raw) {
  int j = blockIdx.x * 256 + threadIdx.x;   // 0..1023
  int b = blockIdx.y;
  int k0 = blockIdx.z * 256;
  const float* xmb = xm + b * DIM + k0;
  const float* w = f1w + (size_t)k0 * (DIM/2) + j;
  float s = 0.f;
#pragma unroll 4
  for (int k = 0; k < 256; ++k) s += xmb[k] * w[(size_t)k * (DIM/2)];
  atomicAdd(&h1raw[b * (DIM/2) + j], s);
}

__global__ void mlp2(const float* __restrict__ h1raw,
                     const float* __restrict__ f1b,
                     const float* __restrict__ f2w,
                     const float* __restrict__ f2b,
                     float* __restrict__ psi_out) {
  int t = threadIdx.x;  // 64 threads
  int b = t >> 4, h = t & 15;
  float s = f2b[h];
  for (int k = 0; k < DIM/2; ++k) {
    float hv = h1raw[b * (DIM/2) + k] * (1.f / (float)SEQ) + f1b[k];
    hv = hv / (1.f + fast_exp(-hv));          // silu
    s += hv * f2w[k * NH + h];
  }
  psi_out[t] = 1.f / (1.f + fast_exp(-s));    // sigmoid
}

// ---------------- GEMM: C(MxN) = A(MxK) @ Bt(NxK)^T ----------------
// MODE 0: bf16 normal out. MODE 2: bf16 transposed per-head (vt).
// MODE 3: f32 normal out, B per-batch (Bt += (m0>>12)*DIM*DIM).
template<int MODE>
__global__ __launch_bounds__(256) void gemm_bt(const bf16* __restrict__ A, int lda,
                                               const bf16* __restrict__ Bt, int ldb,
                                               void* __restrict__ Cv, int ldc, int K) {
  __shared__ bf16 sA[128 * 64];
  __shared__ bf16 sB[128 * 64];
  const int tid = threadIdx.x;
  const int lane = tid & 63;
  const int wave = tid >> 6;
  const int quad = lane >> 4;
  const int wm = (wave & 1) * 64;
  const int wn = (wave >> 1) * 64;
  const size_t m0 = (size_t)blockIdx.y * 128;
  const size_t n0 = (size_t)blockIdx.x * 128;
  const bf16* Bp = Bt;
  if (MODE == 3) Bp += (size_t)(m0 >> 12) * DIM * DIM;
  f32x4 acc[4][4] = {};
  for (int k0 = 0; k0 < K; k0 += 64) {
    stage_tile(A + m0 * lda + k0, lda, sA, lane, wave);
    stage_tile(Bp + n0 * ldb + k0, ldb, sB, lane, wave);
    __syncthreads();
#pragma unroll
    for (int kk = 0; kk < 2; ++kk) {
      const int kc = kk * 4 + quad;
      bf16x8 af[4], bfr[4];
#pragma unroll
      for (int i = 0; i < 4; ++i) af[i] = frag8(sA, wm + i*16 + (lane & 15), kc);
#pragma unroll
      for (int j = 0; j < 4; ++j) bfr[j] = frag8(sB, wn + j*16 + (lane & 15), kc);
#pragma unroll
      for (int i = 0; i < 4; ++i)
#pragma unroll
        for (int j = 0; j < 4; ++j)
          acc[i][j] = MFMA16(af[i], bfr[j], acc[i][j]);
    }
    __syncthreads();
  }
  if (MODE == 2) {
    // transposed per-head store: vt[(b*NH+h)*DKK + dv][nseq]
    const int h = (int)(n0 >> 7) & (NH - 1);
    const int b = (int)(m0 >> 12);
    const int nbase0 = (int)(m0 & 4095) + wm + quad * 4;
    bf16* vt = (bf16*)Cv;
#pragma unroll
    for (int i = 0; i < 4; ++i)
#pragma unroll
      for (int j = 0; j < 4; ++j) {
        int dv = wn + j*16 + (lane & 15);
        bf16x4 p = { (bf16)acc[i][j][0], (bf16)acc[i][j][1],
                     (bf16)acc[i][j][2], (bf16)acc[i][j][3] };
        *(bf16x4*)(vt + ((size_t)(b * NH + h) * DKK + dv) * SEQ + nbase0 + i * 16) = p;
      }
  } else {
#pragma unroll
    for (int i = 0; i < 4; ++i)
#pragma unroll
      for (int j = 0; j < 4; ++j) {
        size_t col = n0 + wn + j*16 + (lane & 15);
        size_t row = m0 + wm + i*16 + quad * 4;
#pragma unroll
        for (int r = 0; r < 4; ++r) {
          if (MODE == 3) ((float*)Cv)[(row + r) * ldc + col] = acc[i][j][r];
          else           ((bf16*)Cv)[(row + r) * ldc + col] = (bf16)acc[i][j][r];
        }
      }
  }
}

// ---------------- fused k-projection + resonance + transposed slow-weighted store ----------------
// kts[(b*NH+h)*DKK + d][n] = k_mod[n][d] * exp(ss[h]*(n-(SEQ-1)))
// LDS budget 48 KB: phase1 sA(16K)+sB(16K) -> becomes K2(32K); sW(16K) for phase-2 W chunks.
__global__ __launch_bounds__(256) void gemm_k_res(const bf16* __restrict__ xb,
                                                  const bf16* __restrict__ Wtk,
                                                  const bf16* __restrict__ Wbt,
                                                  const float* __restrict__ slow_slope,
                                                  bf16* __restrict__ kts) {
  __shared__ bf16 smem[3 * 128 * 64];    // 48 KB
  bf16* sA = smem;
  bf16* sB = smem + 8192;
  bf16* K2 = smem;                       // phase 2: [0, 16384) elements (32 KB)
  bf16* sW = smem + 16384;               // phase 2: 16 KB W chunk
  const int tid = threadIdx.x;
  const int lane = tid & 63;
  const int wave = tid >> 6;
  const int quad = lane >> 4;
  const int wm = (wave & 1) * 64;
  const int wn = (wave >> 1) * 64;
  const int h = blockIdx.x;
  const size_t m0 = (size_t)blockIdx.y * 128;
  const int b = (int)(m0 >> 12);
  const int bh = b * NH + h;
  const float ss = slow_slope[h];

  // phase 1: K-tile = x @ Wk (head h columns)
  const bf16* Ap = xb + m0 * DIM;
  const bf16* Bp = Wtk + (size_t)h * 128 * DIM;
  f32x4 acc[4][4] = {};
  for (int k0 = 0; k0 < DIM; k0 += 64) {
    stage_tile(Ap + k0, DIM, sA, lane, wave);
    stage_tile(Bp + k0, DIM, sB, lane, wave);
    __syncthreads();
#pragma unroll
    for (int kk = 0; kk < 2; ++kk) {
      const int kc = kk * 4 + quad;
      bf16x8 af[4], bfr[4];
#pragma unroll
      for (int i = 0; i < 4; ++i) af[i] = frag8(sA, wm + i*16 + (lane & 15), kc);
#pragma unroll
      for (int j = 0; j < 4; ++j) bfr[j] = frag8(sB, wn + j*16 + (lane & 15), kc);
#pragma unroll
      for (int i = 0; i < 4; ++i)
#pragma unroll
        for (int j = 0; j < 4; ++j)
          acc[i][j] = MFMA16(af[i], bfr[j], acc[i][j]);
    }
    __syncthreads();
  }
  // write K-tile into K2 (swizzled 128-stride, scalar)
#pragma unroll
  for (int i = 0; i < 4; ++i)
#pragma unroll
    for (int j = 0; j < 4; ++j) {
      int c = wn + j*16 + (lane & 15);
#pragma unroll
      for (int r = 0; r < 4; ++r) {
        int row = wm + i*16 + quad*4 + r;
        K2[sqaddr(row, c)] = (bf16)acc[i][j][r];
      }
    }
  __syncthreads();
  // phase 2: R = K2 @ Wb[h]  (Bt = Wbt, staged 128x64 at a time)
  f32x4 accR[4][4] = {};
  const bf16* Wp = Wbt + (size_t)h * DKK * DKK;
#pragma unroll
  for (int k0 = 0; k0 < 128; k0 += 64) {
    stage_tile(Wp + k0, DKK, sW, lane, wave);
    __syncthreads();
#pragma unroll
    for (int kk = 0; kk < 2; ++kk) {
      const int kcl = kk * 4 + quad;
      const int kcg = (k0 >> 3) + kcl;
      bf16x8 af[4], bfr[4];
#pragma unroll
      for (int i = 0; i < 4; ++i) af[i] = frag8w(K2, wm + i*16 + (lane & 15), kcg);
#pragma unroll
      for (int j = 0; j < 4; ++j) bfr[j] = frag8(sW, wn + j*16 + (lane & 15), kcl);
#pragma unroll
      for (int i = 0; i < 4; ++i)
#pragma unroll
        for (int j = 0; j < 4; ++j)
          accR[i][j] = MFMA16(af[i], bfr[j], accR[i][j]);
    }
    __syncthreads();
  }
  // epilogue: k_mod = k*(1+0.5*tanh(R))*inv_sqrt_dk; store *exp(ss*idx), transposed
  float wsv[4][4];
#pragma unroll
  for (int i = 0; i < 4; ++i)
#pragma unroll
    for (int r = 0; r < 4; ++r) {
      int nseq = (int)(m0 & 4095) + wm + i*16 + quad*4 + r;
      wsv[i][r] = fast_exp(ss * (float)(nseq - (SEQ - 1)));
    }
#pragma unroll
  for (int i = 0; i < 4; ++i)
#pragma unroll
    for (int j = 0; j < 4; ++j) {
      int c = wn + j*16 + (lane & 15);
      bf16x4 p;
#pragma unroll
      for (int r = 0; r < 4; ++r) {
        int row = wm + i*16 + quad*4 + r;
        float kv = (float)K2[sqaddr(row, c)];
        float res = fast_tanh(accR[i][j][r]);
        p[r] = (bf16)(kv * (1.f + 0.5f * res) * INV_SQRT_DK * wsv[i][r]);
      }
      int nbase = (int)(m0 & 4095) + wm + i*16 + quad*4;
      *(bf16x4*)(kts + ((size_t)bh * DKK + c) * SEQ + nbase) = p;
    }
}

// ---------------- mcurr: partials[s][bh][{fast,slow}] = Kt(diag w)V over n-split ----------------
__global__ __launch_bounds__(256) void mcurr(const bf16* __restrict__ kts,
                                             const bf16* __restrict__ vt,
                                             const float* __restrict__ rbuf,
                                             float* __restrict__ partials) {
  __shared__ bf16 sK[128 * 64];
  __shared__ bf16 sV[128 * 64];
  const int tid = threadIdx.x;
  const int lane = tid & 63;
  const int wave = tid >> 6;
  const int quad = lane >> 4;
  const int wm = (wave & 1) * 64, wn = (wave >> 1) * 64;
  const int s = blockIdx.x;          // 0..7
  const int bh = blockIdx.y;         // 0..63
  const int h = bh & (NH - 1);
  const bf16* Ap = kts + (size_t)bh * DKK * SEQ;
  const bf16* Bp = vt + (size_t)bh * DKK * SEQ;
  const float* rp = rbuf + (size_t)h * SEQ;
  f32x4 accF[4][4] = {}, accS[4][4] = {};
  for (int k0 = s * 512; k0 < s * 512 + 512; k0 += 64) {
    stage_tile(Ap + k0, SEQ, sK, lane, wave);
    stage_tile(Bp + k0, SEQ, sV, lane, wave);
    __syncthreads();
#pragma unroll
    for (int kk = 0; kk < 2; ++kk) {
      const int kc = kk * 4 + quad;
      const int kn = k0 + kc * 8;
      float rv[8];
      *(f32x4*)rv       = *(const f32x4*)(rp + kn);
      *(f32x4*)(rv + 4) = *(const f32x4*)(rp + kn + 4);
      bf16x8 afS[4], afF[4], bfv[4];
#pragma unroll
      for (int i = 0; i < 4; ++i) afS[i] = frag8(sK, wm + i*16 + (lane & 15), kc);
#pragma unroll
      for (int j = 0; j < 4; ++j) bfv[j] = frag8(sV, wn + j*16 + (lane & 15), kc);
#pragma unroll
      for (int i = 0; i < 4; ++i)
#pragma unroll
        for (int e = 0; e < 8; ++e)
          afF[i][e] = (bf16)((float)afS[i][e] * rv[e]);
#pragma unroll
      for (int i = 0; i < 4; ++i)
#pragma unroll
        for (int j = 0; j < 4; ++j) {
          accS[i][j] = MFMA16(afS[i], bfv[j], accS[i][j]);
          accF[i][j] = MFMA16(afF[i], bfv[j], accF[i][j]);
        }
    }
    __syncthreads();
  }
  float* Pf = partials + ((size_t)(s * 64 + bh) * 2 + 0) * (DKK * DKK);
  float* Ps = partials + ((size_t)(s * 64 + bh) * 2 + 1) * (DKK * DKK);
#pragma unroll
  for (int i = 0; i < 4; ++i)
#pragma unroll
    for (int j = 0; j < 4; ++j) {
      int col = wn + j*16 + (lane & 15);
      int row = wm + i*16 + quad * 4;
#pragma unroll
      for (int r = 0; r < 4; ++r) {
        Pf[(row + r) * DKK + col] = accF[i][j][r];
        Ps[(row + r) * DKK + col] = accS[i][j][r];
      }
    }
}

// ---------------- finalize: M update, (I+S)@M, blend -> Mb (normal order, bf16) ----------------
__global__ __launch_bounds__(256) void finalize(const float* __restrict__ partials,
                                                const float* __restrict__ Mf_prev,
                                                const float* __restrict__ Ms_prev,
                                                const float* __restrict__ inter_fast,
                                                const float* __restrict__ inter_slow,
                                                const float* __restrict__ S_fast,
                                                const float* __restrict__ S_slow,
                                                const float* __restrict__ psi,
                                                float* __restrict__ Mf_out,
                                                float* __restrict__ Ms_out,
                                                bf16* __restrict__ Mb) {
  __shared__ float sMf[128 * 33];
  __shared__ float sMs[128 * 33];
  const int t = threadIdx.x;
  const int bh = blockIdx.x;
  const int h = bh & (NH - 1);
  const int e0 = blockIdx.y * 32;
  const int el = t & 31;
  const int d0 = t >> 5;  // 0..7
  const float inf_ = inter_fast[h], ins_ = inter_slow[h];
  const size_t mb = (size_t)bh * (DKK * DKK);
#pragma unroll
  for (int i = 0; i < 16; ++i) {
    int d = d0 + 8 * i;
    int g = d * DKK + e0 + el;
    float mf = inf_ * Mf_prev[mb + g];
    float ms = ins_ * Ms_prev[mb + g];
#pragma unroll
    for (int s = 0; s < 8; ++s) {
      mf += partials[((size_t)(s * 64 + bh) * 2 + 0) * (DKK*DKK) + g];
      ms += partials[((size_t)(s * 64 + bh) * 2 + 1) * (DKK*DKK) + g];
    }
    Mf_out[mb + g] = mf;
    Ms_out[mb + g] = ms;
    sMf[d * 33 + el] = mf;
    sMs[d * 33 + el] = ms;
  }
  __syncthreads();
  const float p = psi[bh];
  for (int i = 0; i < 16; ++i) {
    int d = d0 + 8 * i;
    float accf = sMf[d * 33 + el];
    float accs = sMs[d * 33 + el];
    const float* Sf = S_fast + (size_t)h * (DKK*DKK) + (size_t)d * DKK;
    const float* Ss = S_slow + (size_t)h * (DKK*DKK) + (size_t)d * DKK;
    for (int k = 0; k < DKK; ++k) {
      accf += Sf[k] * sMf[k * 33 + el];
      accs += Ss[k] * sMs[k * 33 + el];
    }
    float blend = (1.f - p) * accf + p * accs;
    Mb[mb + (size_t)d * DKK + e0 + el] = (bf16)blend;   // Mb[dk][dv]
  }
}

// ---------------- w2: W2t[b][c][h*128+dk] = sum_dv Mb[b,h][dk,dv] * Wo[h*128+dv][c] ----------------
// A = Mb[bh] (128x128, ld 128), Bt = Wto (c-major, ld 2048) offset h*128 cols.
__global__ __launch_bounds__(256) void w2_gemm(const bf16* __restrict__ Mb,
                                               const bf16* __restrict__ Wto,
                                               bf16* __restrict__ W2t) {
  __shared__ bf16 sA[128 * 64];
  __shared__ bf16 sB[128 * 64];
  const int tid = threadIdx.x;
  const int lane = tid & 63;
  const int wave = tid >> 6;
  const int quad = lane >> 4;
  const int wm = (wave & 1) * 64, wn = (wave >> 1) * 64;
  const int c0 = blockIdx.x * 128;
  const int bh = blockIdx.y;
  const int h = bh & (NH - 1), b = bh >> 4;
  const bf16* Ap = Mb + (size_t)bh * DKK * DKK;
  const bf16* Bp = Wto + (size_t)c0 * DIM + h * DKK;
  f32x4 acc[4][4] = {};
#pragma unroll
  for (int k0 = 0; k0 < DKK; k0 += 64) {
    stage_tile(Ap + k0, DKK, sA, lane, wave);
    stage_tile(Bp + k0, DIM, sB, lane, wave);
    __syncthreads();
#pragma unroll
    for (int kk = 0; kk < 2; ++kk) {
      const int kc = kk * 4 + quad;
      bf16x8 af[4], bfr[4];
#pragma unroll
      for (int i = 0; i < 4; ++i) af[i] = frag8(sA, wm + i*16 + (lane & 15), kc);
#pragma unroll
      for (int j = 0; j < 4; ++j) bfr[j] = frag8(sB, wn + j*16 + (lane & 15), kc);
#pragma unroll
      for (int i = 0; i < 4; ++i)
#pragma unroll
        for (int j = 0; j < 4; ++j)
          acc[i][j] = MFMA16(af[i], bfr[j], acc[i][j]);
    }
    __syncthreads();
  }
  // transposed store: W2t[b] + (c0+col)*DIM + h*128 + row   (pack 4 rows)
  bf16* base = W2t + (size_t)b * DIM * DIM + h * DKK;
#pragma unroll
  for (int i = 0; i < 4; ++i)
#pragma unroll
    for (int j = 0; j < 4; ++j) {
      int col = wn + j*16 + (lane & 15);
      int row0 = wm + i*16 + quad * 4;
      bf16x4 p = { (bf16)acc[i][j][0], (bf16)acc[i][j][1],
                   (bf16)acc[i][j][2], (bf16)acc[i][j][3] };
      *(bf16x4*)(base + (size_t)(c0 + col) * DIM + row0) = p;
    }
}

// ---------------- launcher ----------------
extern "C" void kernel_launch(void* const* d_in, const int* in_sizes, int n_in,
                              void* d_out, int out_size, void* d_ws, size_t ws_size,
                              hipStream_t stream) {
  const float* x        = (const float*)d_in[0];
  const float* Mf_prev  = (const float*)d_in[1];
  const float* Ms_prev  = (const float*)d_in[2];
  const float* Wq       = (const float*)d_in[3];
  const float* Wk       = (const float*)d_in[4];
  const float* Wv       = (const float*)d_in[5];
  const float* Wo       = (const float*)d_in[6];
  const float* Wbil     = (const float*)d_in[7];
  const float* fast_slope = (const float*)d_in[8];
  const float* slow_slope = (const float*)d_in[9];
  const float* inter_fast = (const float*)d_in[10];
  const float* inter_slow = (const float*)d_in[11];
  const float* S_fast   = (const float*)d_in[12];
  const float* S_slow   = (const float*)d_in[13];
  const float* f1w      = (const float*)d_in[14];
  const float* f1b      = (const float*)d_in[15];
  const float* f2w      = (const float*)d_in[16];
  const float* f2b      = (const float*)d_in[17];

  char* ws = (char*)d_ws;
  bf16*  xb       = (bf16*)(ws);                    // [0,64Mi); later partials, then W2t
  bf16*  qb       = (bf16*)(ws + 67108864);         // [64,128Mi)
  bf16*  Wtq      = (bf16*)(ws + 134217728);
  bf16*  Wtk      = (bf16*)(ws + 142606336);
  bf16*  Wtv      = (bf16*)(ws + 150994944);
  bf16*  Wto      = (bf16*)(ws + 159383552);
  bf16*  Wbt      = (bf16*)(ws + 167772160);        // 512 KiB
  float* rbuf     = (float*)(ws + 168296448);       // 256 KiB
  bf16*  Mb       = (bf16*)(ws + 168558592);        // 2 MiB
  float* xm       = (float*)(ws + 170655744);       // 32 KiB
  float* h1raw    = (float*)(ws + 170688512);       // 16 KiB
  float* partials = (float*)ws;                     // overlays xb after projections (64 MiB)
  bf16*  W2t      = (bf16*)ws;                      // overlays partials after finalize (32 MiB)

  float* out  = (float*)d_out;
  float* MfO  = out + 33554432;
  float* MsO  = MfO + 1048576;
  float* psiO = MsO + 1048576;
  // kts/vt live in the (not-yet-written) out region: 2 x 64 MiB
  bf16* kts = (bf16*)d_out;
  bf16* vt  = kts + 33554432;

  // conversions / small precompute
  conv_bf16<<<dim3(BN * DIM / 1024), 256, 0, stream>>>(x, xb);
  tconv4<<<dim3(64, 64, 4), dim3(32, 8), 0, stream>>>(Wq, Wk, Wv, Wo, Wtq, Wtk, Wtv, Wto);
  tconvWb<<<dim3(4, 4, NH), dim3(32, 8), 0, stream>>>(Wbil, Wbt);
  rweights<<<dim3(16, 16), 256, 0, stream>>>(fast_slope, slow_slope, rbuf);

  // psi path
  zero_f32<<<dim3(48), 256, 0, stream>>>(xm, BATCH * DIM + BATCH * (DIM/2));
  mean_part<<<dim3(4, 16, 4), 256, 0, stream>>>(xb, xm);
  mlp1<<<dim3(4, 4, 8), 256, 0, stream>>>(xm, f1w, h1raw);
  mlp2<<<dim3(1), 64, 0, stream>>>(h1raw, f1b, f2w, f2b, psiO);

  // projections
  gemm_bt<0><<<dim3(16, 128), 256, 0, stream>>>(xb, DIM, Wtq, DIM, qb, DIM, DIM);
  gemm_bt<2><<<dim3(16, 128), 256, 0, stream>>>(xb, DIM, Wtv, DIM, vt, 0, DIM);
  gemm_k_res<<<dim3(16, 128), 256, 0, stream>>>(xb, Wtk, Wbt, slow_slope, kts);

  // decayed outer products (split-K = 8), partials overlays dead xb
  mcurr<<<dim3(8, 64), 256, 0, stream>>>(kts, vt, rbuf, partials);

  // M update + (I+S)@M + psi blend -> Mb[dk][dv]
  finalize<<<dim3(64, 4), 256, 0, stream>>>(partials, Mf_prev, Ms_prev, inter_fast,
                                            inter_slow, S_fast, S_slow, psiO,
                                            MfO, MsO, Mb);

  // W2t[b] = (Mb @ Wo_head)^T per batch (overlays dead partials)
  w2_gemm<<<dim3(16, 64), 256, 0, stream>>>(Mb, Wto, W2t);

  // out = q @ W2[b]  (f32; overwrites kts/vt which are dead)
  gemm_bt<3><<<dim3(16, 128), 256, 0, stream>>>(qb, DIM, W2t, DIM, out, DIM, DIM);
}

// Round 4
// 1247.073 us; speedup vs baseline: 1.0271x; 1.0271x over previous
//
#include <hip/hip_runtime.h>
#include <math.h>

typedef __bf16 bf16;
typedef __attribute__((ext_vector_type(8))) __bf16 bf16x8;
typedef __attribute__((ext_vector_type(4))) __bf16 bf16x4;
typedef __attribute__((ext_vector_type(2))) __bf16 bf16x2;
typedef __attribute__((ext_vector_type(4))) float f32x4;

#define DIM 2048
#define NH 16
#define DKK 128
#define BATCH 4
#define SEQ 4096
#define BN (BATCH*SEQ)
#define INV_SQRT_DK 0.08838834764831845f

#define MFMA16(a,b,c) __builtin_amdgcn_mfma_f32_16x16x32_bf16((a),(b),(c),0,0,0)

#define GLDS(gp, lp) __builtin_amdgcn_global_load_lds( \
    (const __attribute__((address_space(1))) void*)(gp), \
    (__attribute__((address_space(3))) void*)(lp), 16, 0, 0)

// stage a 128x64 bf16 tile (row stride ld in global) into LDS (stride 64, chunk-XOR swizzle)
__device__ inline void stage_tile(const bf16* __restrict__ g, int ld,
                                  bf16* lds, int lane, int wave) {
  const int rl = lane >> 3;                      // 0..7 row within 8-row group
  const int gc = ((lane & 7) ^ (rl & 7)) << 3;   // swizzled source chunk (elements)
  const bf16* gp = g + (size_t)(wave * 32 + rl) * ld + gc;
#pragma unroll
  for (int t = 0; t < 4; ++t)
    GLDS(gp + (size_t)(t * 8) * ld, lds + (wave * 32 + t * 8) * 64);
}

// read 8 consecutive (global-k) elements for row r at global chunk kc from a swizzled 64-stride tile
__device__ inline bf16x8 frag8(const bf16* lds, int r, int kc) {
  return *(const bf16x8*)(lds + r * 64 + (((kc ^ (r & 7)) << 3)));
}

// swizzled 128-stride tile helpers
__device__ inline bf16x8 frag8w(const bf16* lds, int r, int kc) {
  return *(const bf16x8*)(lds + r * 128 + (((kc ^ (r & 7)) << 3)));
}
__device__ inline int sqaddr(int r, int c) {  // scalar element address in swizzled 128-stride tile
  return r * 128 + ((((c >> 3) ^ (r & 7)) << 3) | (c & 7));
}

__device__ inline float fast_exp(float x) { return __expf(x); }
__device__ inline float fast_tanh(float x) {
  float e2 = __expf(2.f * x);
  return 1.f - 2.f / (e2 + 1.f);
}

// ---------------- conversion kernels ----------------
__global__ __launch_bounds__(256) void conv_bf16(const float* __restrict__ x,
                                                 bf16* __restrict__ y) {
  int i = (blockIdx.x * 256 + threadIdx.x) * 4;
  float4 v = *(const float4*)(x + i);
  bf16x4 o = { (bf16)v.x, (bf16)v.y, (bf16)v.z, (bf16)v.w };
  *(bf16x4*)(y + i) = o;
}

// 3 fused 2048x2048 transposes selected by blockIdx.z (Wk, Wv, Wo)
__global__ __launch_bounds__(256) void tconv3(const float* W0, const float* W1,
                                              const float* W2,
                                              bf16* O0, bf16* O1, bf16* O2) {
  __shared__ float tile[32][33];
  const float* Wp; bf16* Op;
  switch (blockIdx.z) {
    case 0: Wp = W0; Op = O0; break;
    case 1: Wp = W1; Op = O1; break;
    default: Wp = W2; Op = O2; break;
  }
  int c0 = blockIdx.x * 32, r0 = blockIdx.y * 32;
  int tx = threadIdx.x, ty = threadIdx.y;  // (32,8)
#pragma unroll
  for (int i = 0; i < 4; ++i)
    tile[ty + i*8][tx] = Wp[(size_t)(r0 + ty + i*8) * DIM + c0 + tx];
  __syncthreads();
#pragma unroll
  for (int i = 0; i < 4; ++i)
    Op[(size_t)(c0 + ty + i*8) * DIM + r0 + tx] = (bf16)tile[tx][ty + i*8];
}

// per-head 128x128 transpose for W_bilinear
__global__ __launch_bounds__(256) void tconvWb(const float* __restrict__ W,
                                               bf16* __restrict__ Wt) {
  __shared__ float tile[32][33];
  const float* Wp = W + (size_t)blockIdx.z * DKK * DKK;
  bf16* Wtp = Wt + (size_t)blockIdx.z * DKK * DKK;
  int c0 = blockIdx.x * 32, r0 = blockIdx.y * 32;
  int tx = threadIdx.x, ty = threadIdx.y;
#pragma unroll
  for (int i = 0; i < 4; ++i)
    tile[ty + i*8][tx] = Wp[(size_t)(r0 + ty + i*8) * DKK + c0 + tx];
  __syncthreads();
#pragma unroll
  for (int i = 0; i < 4; ++i)
    Wtp[(size_t)(c0 + ty + i*8) * DKK + r0 + tx] = (bf16)tile[tx][ty + i*8];
}

// rbuf[h][n] = exp((fs[h]-ss[h])*(n-(SEQ-1)))
__global__ __launch_bounds__(256) void rweights(const float* __restrict__ fs,
                                                const float* __restrict__ ss,
                                                float* __restrict__ rbuf) {
  int n = blockIdx.x * 256 + threadIdx.x;
  int h = blockIdx.y;
  rbuf[h * SEQ + n] = fast_exp((fs[h] - ss[h]) * (float)(n - (SEQ - 1)));
}

// ---------------- mean + MLP (psi) ----------------
__global__ void zero_f32(float* p, int n) {
  int i = blockIdx.x * 256 + threadIdx.x;
  if (i < n) p[i] = 0.f;
}

__global__ __launch_bounds__(256) void mean_part(const bf16* __restrict__ xb,
                                                 float* __restrict__ xm) {
  int d0 = (blockIdx.x * 256 + threadIdx.x) * 2;
  int b = blockIdx.z;
  const bf16* xp = xb + ((size_t)b * SEQ + (size_t)blockIdx.y * 256) * DIM + d0;
  float s0 = 0.f, s1 = 0.f;
#pragma unroll 8
  for (int n = 0; n < 256; ++n) {
    bf16x2 v = *(const bf16x2*)(xp + (size_t)n * DIM);
    s0 += (float)v[0]; s1 += (float)v[1];
  }
  atomicAdd(&xm[b * DIM + d0], s0);
  atomicAdd(&xm[b * DIM + d0 + 1], s1);
}

// partial dot over k-split; h1raw accumulates raw (unscaled) sums
__global__ __launch_bounds__(256) void mlp1(const float* __restrict__ xm,
                                            const float* __restrict__ f1w,
                                            float* __restrict__ h1raw) {
  int j = blockIdx.x * 256 + threadIdx.x;   // 0..1023
  int b = blockIdx.y;
  int k0 = blockIdx.z * 256;
  const float* xmb = xm + b * DIM + k0;
  const float* w = f1w + (size_t)k0 * (DIM/2) + j;
  float s = 0.f;
#pragma unroll 4
  for (int k = 0; k < 256; ++k) s += xmb[k] * w[(size_t)k * (DIM/2)];
  atomicAdd(&h1raw[b * (DIM/2) + j], s);
}

__global__ void mlp2(const float* __restrict__ h1raw,
                     const float* __restrict__ f1b,
                     const float* __restrict__ f2w,
                     const float* __restrict__ f2b,
                     float* __restrict__ psi_out) {
  int t = threadIdx.x;  // 64 threads
  int b = t >> 4, h = t & 15;
  float s = f2b[h];
  for (int k = 0; k < DIM/2; ++k) {
    float hv = h1raw[b * (DIM/2) + k] * (1.f / (float)SEQ) + f1b[k];
    hv = hv / (1.f + fast_exp(-hv));          // silu
    s += hv * f2w[k * NH + h];
  }
  psi_out[t] = 1.f / (1.f + fast_exp(-s));    // sigmoid
}

// ---------------- GEMM: C(MxN) = A(MxK) @ Bt(NxK)^T ----------------
// MODE 2: bf16 transposed per-head store (vt).
// MODE 3: f32 normal out, Bt per-batch (+= (m0>>12)*DIM*DIM)  [final: out = x @ Wcomb[b]]
// MODE 4: bf16 normal out, A and C per-batch (2048 rows each)  [Wcombt[b] = W2t[b] @ Wq^T]
template<int MODE>
__global__ __launch_bounds__(256) void gemm_bt(const bf16* __restrict__ A, int lda,
                                               const bf16* __restrict__ Bt, int ldb,
                                               void* __restrict__ Cv, int ldc, int K) {
  __shared__ bf16 sA[128 * 64];
  __shared__ bf16 sB[128 * 64];
  const int tid = threadIdx.x;
  const int lane = tid & 63;
  const int wave = tid >> 6;
  const int quad = lane >> 4;
  const int wm = (wave & 1) * 64;
  const int wn = (wave >> 1) * 64;
  const size_t m0 = (size_t)blockIdx.y * 128;
  const size_t n0 = (size_t)blockIdx.x * 128;
  const bf16* Ap = A;
  const bf16* Bp = Bt;
  size_t mrow = m0;            // row offset used against Ap / C
  size_t cbat = 0;             // batch offset for C (MODE 4)
  if (MODE == 3) Bp += (size_t)(m0 >> 12) * DIM * DIM;
  if (MODE == 4) {
    size_t b = m0 >> 11;       // 2048 rows per batch
    Ap += b * DIM * DIM;
    cbat = b * DIM * DIM;
    mrow = m0 & 2047;
  }
  f32x4 acc[4][4] = {};
  for (int k0 = 0; k0 < K; k0 += 64) {
    stage_tile(Ap + mrow * lda + k0, lda, sA, lane, wave);
    stage_tile(Bp + n0 * ldb + k0, ldb, sB, lane, wave);
    __syncthreads();
#pragma unroll
    for (int kk = 0; kk < 2; ++kk) {
      const int kc = kk * 4 + quad;
      bf16x8 af[4], bfr[4];
#pragma unroll
      for (int i = 0; i < 4; ++i) af[i] = frag8(sA, wm + i*16 + (lane & 15), kc);
#pragma unroll
      for (int j = 0; j < 4; ++j) bfr[j] = frag8(sB, wn + j*16 + (lane & 15), kc);
#pragma unroll
      for (int i = 0; i < 4; ++i)
#pragma unroll
        for (int j = 0; j < 4; ++j)
          acc[i][j] = MFMA16(af[i], bfr[j], acc[i][j]);
    }
    __syncthreads();
  }
  if (MODE == 2) {
    // transposed per-head store: vt[(b*NH+h)*DKK + dv][nseq]
    const int h = (int)(n0 >> 7) & (NH - 1);
    const int b = (int)(m0 >> 12);
    const int nbase0 = (int)(m0 & 4095) + wm + quad * 4;
    bf16* vt = (bf16*)Cv;
#pragma unroll
    for (int i = 0; i < 4; ++i)
#pragma unroll
      for (int j = 0; j < 4; ++j) {
        int dv = wn + j*16 + (lane & 15);
        bf16x4 p = { (bf16)acc[i][j][0], (bf16)acc[i][j][1],
                     (bf16)acc[i][j][2], (bf16)acc[i][j][3] };
        *(bf16x4*)(vt + ((size_t)(b * NH + h) * DKK + dv) * SEQ + nbase0 + i * 16) = p;
      }
  } else {
#pragma unroll
    for (int i = 0; i < 4; ++i)
#pragma unroll
      for (int j = 0; j < 4; ++j) {
        size_t col = n0 + wn + j*16 + (lane & 15);
        size_t row = mrow + wm + i*16 + quad * 4;
#pragma unroll
        for (int r = 0; r < 4; ++r) {
          if (MODE == 3) ((float*)Cv)[(row + r) * ldc + col] = acc[i][j][r];
          else           ((bf16*)Cv)[cbat + (row + r) * ldc + col] = (bf16)acc[i][j][r];
        }
      }
  }
}

// ---------------- fused k-projection + resonance + transposed slow-weighted store ----------------
// kts[(b*NH+h)*DKK + d][n] = k_mod[n][d] * exp(ss[h]*(n-(SEQ-1)))
// LDS budget 48 KB: phase1 sA(16K)+sB(16K) -> becomes K2(32K); sW(16K) for phase-2 W chunks.
__global__ __launch_bounds__(256) void gemm_k_res(const bf16* __restrict__ xb,
                                                  const bf16* __restrict__ Wtk,
                                                  const bf16* __restrict__ Wbt,
                                                  const float* __restrict__ slow_slope,
                                                  bf16* __restrict__ kts) {
  __shared__ bf16 smem[3 * 128 * 64];    // 48 KB
  bf16* sA = smem;
  bf16* sB = smem + 8192;
  bf16* K2 = smem;                       // phase 2: [0, 16384) elements (32 KB)
  bf16* sW = smem + 16384;               // phase 2: 16 KB W chunk
  const int tid = threadIdx.x;
  const int lane = tid & 63;
  const int wave = tid >> 6;
  const int quad = lane >> 4;
  const int wm = (wave & 1) * 64;
  const int wn = (wave >> 1) * 64;
  const int h = blockIdx.x;
  const size_t m0 = (size_t)blockIdx.y * 128;
  const int b = (int)(m0 >> 12);
  const int bh = b * NH + h;
  const float ss = slow_slope[h];

  // phase 1: K-tile = x @ Wk (head h columns)
  const bf16* Ap = xb + m0 * DIM;
  const bf16* Bp = Wtk + (size_t)h * 128 * DIM;
  f32x4 acc[4][4] = {};
  for (int k0 = 0; k0 < DIM; k0 += 64) {
    stage_tile(Ap + k0, DIM, sA, lane, wave);
    stage_tile(Bp + k0, DIM, sB, lane, wave);
    __syncthreads();
#pragma unroll
    for (int kk = 0; kk < 2; ++kk) {
      const int kc = kk * 4 + quad;
      bf16x8 af[4], bfr[4];
#pragma unroll
      for (int i = 0; i < 4; ++i) af[i] = frag8(sA, wm + i*16 + (lane & 15), kc);
#pragma unroll
      for (int j = 0; j < 4; ++j) bfr[j] = frag8(sB, wn + j*16 + (lane & 15), kc);
#pragma unroll
      for (int i = 0; i < 4; ++i)
#pragma unroll
        for (int j = 0; j < 4; ++j)
          acc[i][j] = MFMA16(af[i], bfr[j], acc[i][j]);
    }
    __syncthreads();
  }
  // write K-tile into K2 (swizzled 128-stride, scalar)
#pragma unroll
  for (int i = 0; i < 4; ++i)
#pragma unroll
    for (int j = 0; j < 4; ++j) {
      int c = wn + j*16 + (lane & 15);
#pragma unroll
      for (int r = 0; r < 4; ++r) {
        int row = wm + i*16 + quad*4 + r;
        K2[sqaddr(row, c)] = (bf16)acc[i][j][r];
      }
    }
  __syncthreads();
  // phase 2: R = K2 @ Wb[h]  (Bt = Wbt, staged 128x64 at a time)
  f32x4 accR[4][4] = {};
  const bf16* Wp = Wbt + (size_t)h * DKK * DKK;
#pragma unroll
  for (int k0 = 0; k0 < 128; k0 += 64) {
    stage_tile(Wp + k0, DKK, sW, lane, wave);
    __syncthreads();
#pragma unroll
    for (int kk = 0; kk < 2; ++kk) {
      const int kcl = kk * 4 + quad;
      const int kcg = (k0 >> 3) + kcl;
      bf16x8 af[4], bfr[4];
#pragma unroll
      for (int i = 0; i < 4; ++i) af[i] = frag8w(K2, wm + i*16 + (lane & 15), kcg);
#pragma unroll
      for (int j = 0; j < 4; ++j) bfr[j] = frag8(sW, wn + j*16 + (lane & 15), kcl);
#pragma unroll
      for (int i = 0; i < 4; ++i)
#pragma unroll
        for (int j = 0; j < 4; ++j)
          accR[i][j] = MFMA16(af[i], bfr[j], accR[i][j]);
    }
    __syncthreads();
  }
  // epilogue: k_mod = k*(1+0.5*tanh(R))*inv_sqrt_dk; store *exp(ss*idx), transposed
  float wsv[4][4];
#pragma unroll
  for (int i = 0; i < 4; ++i)
#pragma unroll
    for (int r = 0; r < 4; ++r) {
      int nseq = (int)(m0 & 4095) + wm + i*16 + quad*4 + r;
      wsv[i][r] = fast_exp(ss * (float)(nseq - (SEQ - 1)));
    }
#pragma unroll
  for (int i = 0; i < 4; ++i)
#pragma unroll
    for (int j = 0; j < 4; ++j) {
      int c = wn + j*16 + (lane & 15);
      bf16x4 p;
#pragma unroll
      for (int r = 0; r < 4; ++r) {
        int row = wm + i*16 + quad*4 + r;
        float kv = (float)K2[sqaddr(row, c)];
        float res = fast_tanh(accR[i][j][r]);
        p[r] = (bf16)(kv * (1.f + 0.5f * res) * INV_SQRT_DK * wsv[i][r]);
      }
      int nbase = (int)(m0 & 4095) + wm + i*16 + quad*4;
      *(bf16x4*)(kts + ((size_t)bh * DKK + c) * SEQ + nbase) = p;
    }
}

// ---------------- mcurr: partials[s][bh][{fast,slow}] = Kt(diag w)V over n-split ----------------
__global__ __launch_bounds__(256) void mcurr(const bf16* __restrict__ kts,
                                             const bf16* __restrict__ vt,
                                             const float* __restrict__ rbuf,
                                             float* __restrict__ partials) {
  __shared__ bf16 sK[128 * 64];
  __shared__ bf16 sV[128 * 64];
  const int tid = threadIdx.x;
  const int lane = tid & 63;
  const int wave = tid >> 6;
  const int quad = lane >> 4;
  const int wm = (wave & 1) * 64, wn = (wave >> 1) * 64;
  const int s = blockIdx.x;          // 0..7
  const int bh = blockIdx.y;         // 0..63
  const int h = bh & (NH - 1);
  const bf16* Ap = kts + (size_t)bh * DKK * SEQ;
  const bf16* Bp = vt + (size_t)bh * DKK * SEQ;
  const float* rp = rbuf + (size_t)h * SEQ;
  f32x4 accF[4][4] = {}, accS[4][4] = {};
  for (int k0 = s * 512; k0 < s * 512 + 512; k0 += 64) {
    stage_tile(Ap + k0, SEQ, sK, lane, wave);
    stage_tile(Bp + k0, SEQ, sV, lane, wave);
    __syncthreads();
#pragma unroll
    for (int kk = 0; kk < 2; ++kk) {
      const int kc = kk * 4 + quad;
      const int kn = k0 + kc * 8;
      float rv[8];
      *(f32x4*)rv       = *(const f32x4*)(rp + kn);
      *(f32x4*)(rv + 4) = *(const f32x4*)(rp + kn + 4);
      bf16x8 afS[4], afF[4], bfv[4];
#pragma unroll
      for (int i = 0; i < 4; ++i) afS[i] = frag8(sK, wm + i*16 + (lane & 15), kc);
#pragma unroll
      for (int j = 0; j < 4; ++j) bfv[j] = frag8(sV, wn + j*16 + (lane & 15), kc);
#pragma unroll
      for (int i = 0; i < 4; ++i)
#pragma unroll
        for (int e = 0; e < 8; ++e)
          afF[i][e] = (bf16)((float)afS[i][e] * rv[e]);
#pragma unroll
      for (int i = 0; i < 4; ++i)
#pragma unroll
        for (int j = 0; j < 4; ++j) {
          accS[i][j] = MFMA16(afS[i], bfv[j], accS[i][j]);
          accF[i][j] = MFMA16(afF[i], bfv[j], accF[i][j]);
        }
    }
    __syncthreads();
  }
  float* Pf = partials + ((size_t)(s * 64 + bh) * 2 + 0) * (DKK * DKK);
  float* Ps = partials + ((size_t)(s * 64 + bh) * 2 + 1) * (DKK * DKK);
#pragma unroll
  for (int i = 0; i < 4; ++i)
#pragma unroll
    for (int j = 0; j < 4; ++j) {
      int col = wn + j*16 + (lane & 15);
      int row = wm + i*16 + quad * 4;
#pragma unroll
      for (int r = 0; r < 4; ++r) {
        Pf[(row + r) * DKK + col] = accF[i][j][r];
        Ps[(row + r) * DKK + col] = accS[i][j][r];
      }
    }
}

// ---------------- finalize: M update, (I+S)@M, blend -> Mb (normal order, bf16) ----------------
__global__ __launch_bounds__(256) void finalize(const float* __restrict__ partials,
                                                const float* __restrict__ Mf_prev,
                                                const float* __restrict__ Ms_prev,
                                                const float* __restrict__ inter_fast,
                                                const float* __restrict__ inter_slow,
                                                const float* __restrict__ S_fast,
                                                const float* __restrict__ S_slow,
                                                const float* __restrict__ psi,
                                                float* __restrict__ Mf_out,
                                                float* __restrict__ Ms_out,
                                                bf16* __restrict__ Mb) {
  __shared__ float sMf[128 * 33];
  __shared__ float sMs[128 * 33];
  const int t = threadIdx.x;
  const int bh = blockIdx.x;
  const int h = bh & (NH - 1);
  const int e0 = blockIdx.y * 32;
  const int el = t & 31;
  const int d0 = t >> 5;  // 0..7
  const float inf_ = inter_fast[h], ins_ = inter_slow[h];
  const size_t mb = (size_t)bh * (DKK * DKK);
#pragma unroll
  for (int i = 0; i < 16; ++i) {
    int d = d0 + 8 * i;
    int g = d * DKK + e0 + el;
    float mf = inf_ * Mf_prev[mb + g];
    float ms = ins_ * Ms_prev[mb + g];
#pragma unroll
    for (int s = 0; s < 8; ++s) {
      mf += partials[((size_t)(s * 64 + bh) * 2 + 0) * (DKK*DKK) + g];
      ms += partials[((size_t)(s * 64 + bh) * 2 + 1) * (DKK*DKK) + g];
    }
    Mf_out[mb + g] = mf;
    Ms_out[mb + g] = ms;
    sMf[d * 33 + el] = mf;
    sMs[d * 33 + el] = ms;
  }
  __syncthreads();
  const float p = psi[bh];
  for (int i = 0; i < 16; ++i) {
    int d = d0 + 8 * i;
    float accf = sMf[d * 33 + el];
    float accs = sMs[d * 33 + el];
    const float* Sf = S_fast + (size_t)h * (DKK*DKK) + (size_t)d * DKK;
    const float* Ss = S_slow + (size_t)h * (DKK*DKK) + (size_t)d * DKK;
    for (int k = 0; k < DKK; ++k) {
      accf += Sf[k] * sMf[k * 33 + el];
      accs += Ss[k] * sMs[k * 33 + el];
    }
    float blend = (1.f - p) * accf + p * accs;
    Mb[mb + (size_t)d * DKK + e0 + el] = (bf16)blend;   // Mb[dk][dv]
  }
}

// ---------------- w2: W2t[b][c][h*128+dk] = sum_dv Mb[b,h][dk,dv] * Wo[h*128+dv][c] ----------------
// A = Mb[bh] (128x128, ld 128), Bt = Wto (c-major, ld 2048) offset h*128 cols.
__global__ __launch_bounds__(256) void w2_gemm(const bf16* __restrict__ Mb,
                                               const bf16* __restrict__ Wto,
                                               bf16* __restrict__ W2t) {
  __shared__ bf16 sA[128 * 64];
  __shared__ bf16 sB[128 * 64];
  const int tid = threadIdx.x;
  const int lane = tid & 63;
  const int wave = tid >> 6;
  const int quad = lane >> 4;
  const int wm = (wave & 1) * 64, wn = (wave >> 1) * 64;
  const int c0 = blockIdx.x * 128;
  const int bh = blockIdx.y;
  const int h = bh & (NH - 1), b = bh >> 4;
  const bf16* Ap = Mb + (size_t)bh * DKK * DKK;
  const bf16* Bp = Wto + (size_t)c0 * DIM + h * DKK;
  f32x4 acc[4][4] = {};
#pragma unroll
  for (int k0 = 0; k0 < DKK; k0 += 64) {
    stage_tile(Ap + k0, DKK, sA, lane, wave);
    stage_tile(Bp + k0, DIM, sB, lane, wave);
    __syncthreads();
#pragma unroll
    for (int kk = 0; kk < 2; ++kk) {
      const int kc = kk * 4 + quad;
      bf16x8 af[4], bfr[4];
#pragma unroll
      for (int i = 0; i < 4; ++i) af[i] = frag8(sA, wm + i*16 + (lane & 15), kc);
#pragma unroll
      for (int j = 0; j < 4; ++j) bfr[j] = frag8(sB, wn + j*16 + (lane & 15), kc);
#pragma unroll
      for (int i = 0; i < 4; ++i)
#pragma unroll
        for (int j = 0; j < 4; ++j)
          acc[i][j] = MFMA16(af[i], bfr[j], acc[i][j]);
    }
    __syncthreads();
  }
  // transposed store: W2t[b] + (c0+col)*DIM + h*128 + row   (pack 4 rows)
  bf16* base = W2t + (size_t)b * DIM * DIM + h * DKK;
#pragma unroll
  for (int i = 0; i < 4; ++i)
#pragma unroll
    for (int j = 0; j < 4; ++j) {
      int col = wn + j*16 + (lane & 15);
      int row0 = wm + i*16 + quad * 4;
      bf16x4 p = { (bf16)acc[i][j][0], (bf16)acc[i][j][1],
                   (bf16)acc[i][j][2], (bf16)acc[i][j][3] };
      *(bf16x4*)(base + (size_t)(c0 + col) * DIM + row0) = p;
    }
}

// ---------------- launcher ----------------
extern "C" void kernel_launch(void* const* d_in, const int* in_sizes, int n_in,
                              void* d_out, int out_size, void* d_ws, size_t ws_size,
                              hipStream_t stream) {
  const float* x        = (const float*)d_in[0];
  const float* Mf_prev  = (const float*)d_in[1];
  const float* Ms_prev  = (const float*)d_in[2];
  const float* Wq       = (const float*)d_in[3];
  const float* Wk       = (const float*)d_in[4];
  const float* Wv       = (const float*)d_in[5];
  const float* Wo       = (const float*)d_in[6];
  const float* Wbil     = (const float*)d_in[7];
  const float* fast_slope = (const float*)d_in[8];
  const float* slow_slope = (const float*)d_in[9];
  const float* inter_fast = (const float*)d_in[10];
  const float* inter_slow = (const float*)d_in[11];
  const float* S_fast   = (const float*)d_in[12];
  const float* S_slow   = (const float*)d_in[13];
  const float* f1w      = (const float*)d_in[14];
  const float* f1b      = (const float*)d_in[15];
  const float* f2w      = (const float*)d_in[16];
  const float* f2b      = (const float*)d_in[17];

  char* ws = (char*)d_ws;
  bf16*  xb       = (bf16*)(ws);                    // [0,64Mi) -- alive until final GEMM
  // [64,128Mi): partials (64Mi) -> overlaid by W2t [64,96Mi) + Wcombt [96,128Mi)
  float* partials = (float*)(ws + 67108864);
  bf16*  W2t      = (bf16*)(ws + 67108864);
  bf16*  Wcombt   = (bf16*)(ws + 100663296);
  bf16*  Wqb      = (bf16*)(ws + 134217728);        // 8 MiB each
  bf16*  Wtk      = (bf16*)(ws + 142606336);
  bf16*  Wtv      = (bf16*)(ws + 150994944);
  bf16*  Wto      = (bf16*)(ws + 159383552);
  bf16*  Wbt      = (bf16*)(ws + 167772160);        // 512 KiB
  float* rbuf     = (float*)(ws + 168296448);       // 256 KiB
  bf16*  Mb       = (bf16*)(ws + 168558592);        // 2 MiB
  float* xm       = (float*)(ws + 170655744);       // 32 KiB
  float* h1raw    = (float*)(ws + 170688512);       // 16 KiB

  float* out  = (float*)d_out;
  float* MfO  = out + 33554432;
  float* MsO  = MfO + 1048576;
  float* psiO = MsO + 1048576;
  // kts/vt live in the (not-yet-written) out region: 2 x 64 MiB
  bf16* kts = (bf16*)d_out;
  bf16* vt  = kts + 33554432;

  // conversions / small precompute
  conv_bf16<<<dim3(BN * DIM / 1024), 256, 0, stream>>>(x, xb);
  conv_bf16<<<dim3(DIM * DIM / 1024), 256, 0, stream>>>(Wq, Wqb);
  tconv3<<<dim3(64, 64, 3), dim3(32, 8), 0, stream>>>(Wk, Wv, Wo, Wtk, Wtv, Wto);
  tconvWb<<<dim3(4, 4, NH), dim3(32, 8), 0, stream>>>(Wbil, Wbt);
  rweights<<<dim3(16, 16), 256, 0, stream>>>(fast_slope, slow_slope, rbuf);

  // psi path
  zero_f32<<<dim3(48), 256, 0, stream>>>(xm, BATCH * DIM + BATCH * (DIM/2));
  mean_part<<<dim3(4, 16, 4), 256, 0, stream>>>(xb, xm);
  mlp1<<<dim3(4, 4, 8), 256, 0, stream>>>(xm, f1w, h1raw);
  mlp2<<<dim3(1), 64, 0, stream>>>(h1raw, f1b, f2w, f2b, psiO);

  // projections (q-projection eliminated via weight composition)
  gemm_bt<2><<<dim3(16, 128), 256, 0, stream>>>(xb, DIM, Wtv, DIM, vt, 0, DIM);
  gemm_k_res<<<dim3(16, 128), 256, 0, stream>>>(xb, Wtk, Wbt, slow_slope, kts);

  // decayed outer products (split-K = 8)
  mcurr<<<dim3(8, 64), 256, 0, stream>>>(kts, vt, rbuf, partials);

  // M update + (I+S)@M + psi blend -> Mb[dk][dv]
  finalize<<<dim3(64, 4), 256, 0, stream>>>(partials, Mf_prev, Ms_prev, inter_fast,
                                            inter_slow, S_fast, S_slow, psiO,
                                            MfO, MsO, Mb);

  // W2t[b][c][hdk] = (Mb_blend @ Wo_head)^T   (overlays dead partials)
  w2_gemm<<<dim3(16, 64), 256, 0, stream>>>(Mb, Wto, W2t);

  // Wcombt[b][c][d] = sum_hdk W2t[b][c][hdk] * Wq[d][hdk]   (4 batches x 2048^2, MODE 4)
  gemm_bt<4><<<dim3(16, 64), 256, 0, stream>>>(W2t, DIM, Wqb, DIM, Wcombt, DIM, DIM);

  // out = x @ Wcomb[b]  (f32; overwrites kts/vt which are dead)
  gemm_bt<3><<<dim3(16, 128), 256, 0, stream>>>(xb, DIM, Wcombt, DIM, out, DIM, DIM);
}